// Round 1
// baseline (921.626 us; speedup 1.0000x reference)
//
#include <hip/hip_runtime.h>

#define NB 512   // batch
#define NT 512   // time steps
#define NL 126   // labels
#define NS 128   // states = NL + 2 (start=126, end=127)

// One block per batch element. 256 threads: j = tid & 127 (column),
// half = tid >> 7 (i-range of 64). expT' column held in 64 VGPRs/thread.
__global__ __launch_bounds__(256) void crf_kernel(
    const float* __restrict__ emissions,   // [NB, NT, NL] f32
    const int*   __restrict__ labels,      // [NB, NT] i32
    const float* __restrict__ trans,       // [NS, NS] f32
    float*       __restrict__ out)         // [1] f32 (pre-zeroed)
{
  const int b    = blockIdx.x;
  const int tid  = threadIdx.x;
  const int j    = tid & (NS - 1);
  const int half = tid >> 7;
  const int i0   = half * 64;

  __shared__ __align__(16) float u_lds[NS]; // u[i] = exp(q[i] - Qref)
  __shared__ float redh[256];
  __shared__ float reds[256];
  __shared__ float scal_s[4];
  __shared__ float scal_m[4];

  const float* em  = emissions + (size_t)b * NT * NL;
  const int*   lab = labels + b * NT;

  // ---- register table: tab[ii] = exp(T[i0+ii][j] - colmax_j) ----
  float tab[64];
  float cmax = -3.0e38f;
  #pragma unroll
  for (int ii = 0; ii < 64; ii++) {
    float v = trans[(i0 + ii) * NS + j];
    tab[ii] = v;
    cmax = fmaxf(cmax, v);
  }
  redh[tid] = cmax;           // redh[half*128 + j]
  __syncthreads();
  const float tau = fmaxf(redh[j], redh[NS + j]);
  #pragma unroll
  for (int ii = 0; ii < 64; ii++)
    tab[ii] = __expf(tab[ii] - tau);

  // ---- real (gold) path score, partial per thread ----
  float realp = 0.f;
  for (int t = tid; t < NT; t += 256) {
    int lt = lab[t];
    int nx = (t + 1 < NT) ? lab[t + 1] : (NL + 1);
    realp += em[t * NL + lt] + trans[lt * NS + nx];
  }
  if (tid == 0) realp += trans[NL * NS + lab[0]];

  // ---- init scan: q = E[0] (0 at state 126, -1000 elsewhere) ----
  __syncthreads();            // redh reuse guard
  if (tid < NS) u_lds[tid] = (tid == NL) ? 1.0f : 0.0f;
  float Q = 0.f, C = 0.f;
  __syncthreads();

  for (int t = 0; t <= NT; t++) {
    // inner: partial col-max h and col-sum s over this thread's i-half
    float h = 0.f, s = 0.f;
    const float4* up = (const float4*)(u_lds + i0);
    #pragma unroll
    for (int ii = 0; ii < 16; ii++) {
      float4 uu = up[ii];                 // broadcast ds_read_b128
      float p0 = uu.x * tab[4*ii+0];
      float p1 = uu.y * tab[4*ii+1];
      float p2 = uu.z * tab[4*ii+2];
      float p3 = uu.w * tab[4*ii+3];
      h = fmaxf(h, fmaxf(fmaxf(p0, p1), fmaxf(p2, p3)));
      s += (p0 + p1) + (p2 + p3);
    }
    redh[tid] = h;
    reds[tid] = s;
    __syncthreads();

    float r = -3.0e38f, contrib = 0.f;
    if (tid < NS) {
      float hj = fmaxf(fmaxf(redh[tid], redh[NS + tid]), 1e-37f);
      float sj = reds[tid] + reds[NS + tid];
      contrib = sj * __builtin_amdgcn_rcpf(hj);   // column S-contribution
      float obs;
      if (t < NT) obs = (tid < NL) ? em[t * NL + tid] : -1000.0f;
      else        obs = (tid == NL + 1) ? 0.0f : -1000.0f;
      r = obs + tau + __logf(hj);       // q_new[j] - Qref
    }
    // block reduce: S = sum(contrib), maxr = max(r)
    float rs = contrib, rm = r;
    #pragma unroll
    for (int off = 32; off; off >>= 1) {
      rs += __shfl_down(rs, off, 64);
      rm  = fmaxf(rm, __shfl_down(rm, off, 64));
    }
    if ((tid & 63) == 0) { scal_s[tid >> 6] = rs; scal_m[tid >> 6] = rm; }
    __syncthreads();
    float S    = (scal_s[0] + scal_s[1]) + (scal_s[2] + scal_s[3]);
    float maxr = fmaxf(fmaxf(scal_m[0], scal_m[1]),
                       fmaxf(scal_m[2], scal_m[3]));
    C += __logf(S);
    Q += maxr;
    if (tid < NS) u_lds[tid] = __expf(r - maxr);
    __syncthreads();
  }

  // ---- total_b = Q + C + log(sum u);  out += total_b - real_b ----
  float su = (tid < NS) ? u_lds[tid] : 0.f;
  float rr = realp;
  #pragma unroll
  for (int off = 32; off; off >>= 1) {
    su += __shfl_down(su, off, 64);
    rr += __shfl_down(rr, off, 64);
  }
  if ((tid & 63) == 0) { scal_s[tid >> 6] = su; scal_m[tid >> 6] = rr; }
  __syncthreads();
  if (tid == 0) {
    float sumu    = (scal_s[0] + scal_s[1]) + (scal_s[2] + scal_s[3]);
    float realsum = (scal_m[0] + scal_m[1]) + (scal_m[2] + scal_m[3]);
    float total   = Q + C + __logf(sumu);
    atomicAdd(out, total - realsum);
  }
}

extern "C" void kernel_launch(void* const* d_in, const int* in_sizes, int n_in,
                              void* d_out, int out_size, void* d_ws, size_t ws_size,
                              hipStream_t stream) {
  const float* em  = (const float*)d_in[0];
  const int*   lab = (const int*)d_in[1];
  const float* tr  = (const float*)d_in[2];
  hipMemsetAsync(d_out, 0, sizeof(float), stream);
  crf_kernel<<<NB, 256, 0, stream>>>(em, lab, tr, (float*)d_out);
}

// Round 2
// 827.398 us; speedup vs baseline: 1.1139x; 1.1139x over previous
//
#include <hip/hip_runtime.h>

#define NB 512   // batch
#define NT 512   // time steps
#define NL 126   // labels
#define NS 128   // states = NL + 2 (start=126, end=127)

// DPP wave64 reductions: row_shr 1/2/4/8 then row_bcast:15 (rows 1,3) and
// row_bcast:31 (rows 2,3). old = 0 is the identity for add and for max of
// non-negative values. Result lands in lane 63.
#define DPP_ADD(x, ctrl, rm) \
  ((x) + __int_as_float(__builtin_amdgcn_update_dpp(0, __float_as_int(x), (ctrl), (rm), 0xf, false)))
#define DPP_MAX(x, ctrl, rm) \
  fmaxf((x), __int_as_float(__builtin_amdgcn_update_dpp(0, __float_as_int(x), (ctrl), (rm), 0xf, false)))

__global__ __launch_bounds__(256) void crf_kernel(
    const float* __restrict__ emissions,   // [NB, NT, NL] f32
    const int*   __restrict__ labels,      // [NB, NT] i32
    const float* __restrict__ trans,       // [NS, NS] f32
    float*       __restrict__ out)         // [1] f32 (pre-zeroed)
{
  const int b    = blockIdx.x;
  const int tid  = threadIdx.x;
  const int j    = tid & (NS - 1);
  const int half = tid >> 7;
  const int i0   = half * 64;

  __shared__ __align__(16) float u_lds[NS]; // u[i] = exp(q[i] - Qref)
  __shared__ float redh[2 * NS];
  __shared__ float reds[2 * NS];
  __shared__ float scal_s[4];
  __shared__ float scal_m[4];

  const float* em  = emissions + (size_t)b * NT * NL;
  const int*   lab = labels + b * NT;

  // ---- register table: tab[ii] = exp(T[i0+ii][j] - colmax_j) ----
  float tab[64];
  float cmax = -3.0e38f;
  #pragma unroll
  for (int ii = 0; ii < 64; ii++) {
    float v = trans[(i0 + ii) * NS + j];
    tab[ii] = v;
    cmax = fmaxf(cmax, v);
  }
  redh[tid] = cmax;           // redh[half*128 + j]
  __syncthreads();
  const float tau = fmaxf(redh[j], redh[NS + j]);
  #pragma unroll
  for (int ii = 0; ii < 64; ii++)
    tab[ii] = __expf(tab[ii] - tau);

  // ---- real (gold) path score, partial per thread ----
  float realp = 0.f;
  for (int t = tid; t < NT; t += 256) {
    int lt = lab[t];
    int nx = (t + 1 < NT) ? lab[t + 1] : (NL + 1);
    realp += em[t * NL + lt] + trans[lt * NS + nx];
  }
  if (tid == 0) realp += trans[NL * NS + lab[0]];

  // ---- init scan ----
  __syncthreads();            // redh reuse guard
  if (tid < NS) u_lds[tid] = (tid == NL) ? 1.0f : 0.0f;
  float Q = 0.f, C = 0.f;
  __syncthreads();

  for (int t = 0; t <= NT; t++) {
    // wave0: prefetch this step's emissions (drained by barrier A; the
    // inner loop below covers the latency)
    float em0 = 0.f, em1 = 0.f;
    if (tid < 64 && t < NT) {
      em0 = em[t * NL + tid];
      if (tid + 64 < NL) em1 = em[t * NL + tid + 64];
    }

    // inner: partial col-max h and col-sum s over this thread's i-half
    float ha = 0.f, hb = 0.f, sa = 0.f, sb = 0.f;
    const float4* up = (const float4*)(u_lds + i0);
    #pragma unroll
    for (int ii = 0; ii < 16; ii++) {
      float4 uu = up[ii];                 // broadcast ds_read_b128
      float p0 = uu.x * tab[4*ii+0];
      float p1 = uu.y * tab[4*ii+1];
      float p2 = uu.z * tab[4*ii+2];
      float p3 = uu.w * tab[4*ii+3];
      ha = fmaxf(ha, fmaxf(p0, p1));
      hb = fmaxf(hb, fmaxf(p2, p3));
      sa += p0 + p1;
      sb += p2 + p3;
    }
    redh[tid] = fmaxf(ha, hb);
    reds[tid] = sa + sb;
    __syncthreads();            // barrier A

    if (tid < 64) {
      const int l = tid;
      // combine the two i-halves for columns l and l+64
      float h0 = fmaxf(fmaxf(redh[l],      redh[NS + l]),      1e-37f);
      float h1 = fmaxf(fmaxf(redh[64 + l], redh[NS + 64 + l]), 1e-37f);
      float s0 = reds[l]      + reds[NS + l];
      float s1 = reds[64 + l] + reds[NS + 64 + l];
      float contrib = s0 * __builtin_amdgcn_rcpf(h0)
                    + s1 * __builtin_amdgcn_rcpf(h1);
      float e0, e1;
      if (t < NT) {
        e0 = __expf(em0);
        e1 = (l + 64 < NL) ? __expf(em1) : 0.f;   // cols 126,127: obs=-1000
      } else {
        e0 = 0.f;
        e1 = (l == 63) ? 1.f : 0.f;               // col 127 gets obs=0
      }
      float w0 = h0 * e0, w1 = h1 * e1;
      float wm = fmaxf(w0, w1);

      // DPP reductions over 64 lanes (result in lane 63)
      contrib = DPP_ADD(contrib, 0x111, 0xf);
      wm      = DPP_MAX(wm,      0x111, 0xf);
      contrib = DPP_ADD(contrib, 0x112, 0xf);
      wm      = DPP_MAX(wm,      0x112, 0xf);
      contrib = DPP_ADD(contrib, 0x114, 0xf);
      wm      = DPP_MAX(wm,      0x114, 0xf);
      contrib = DPP_ADD(contrib, 0x118, 0xf);
      wm      = DPP_MAX(wm,      0x118, 0xf);
      contrib = DPP_ADD(contrib, 0x142, 0xa);  // row_bcast:15 -> rows 1,3
      wm      = DPP_MAX(wm,      0x142, 0xa);
      contrib = DPP_ADD(contrib, 0x143, 0xc);  // row_bcast:31 -> rows 2,3
      wm      = DPP_MAX(wm,      0x143, 0xc);
      float S = __int_as_float(__builtin_amdgcn_readlane(__float_as_int(contrib), 63));
      float W = __int_as_float(__builtin_amdgcn_readlane(__float_as_int(wm), 63));

      float rW = __builtin_amdgcn_rcpf(W);
      u_lds[l]      = w0 * rW;
      u_lds[l + 64] = w1 * rW;
      C += __logf(S);            // off the u-critical-path
      Q += tau + __logf(W);
    }
    __syncthreads();            // barrier B: u visible to all
  }

  // ---- total_b = Q + C + log(sum u);  out += total_b - real_b ----
  float su = (tid < NS) ? u_lds[tid] : 0.f;
  float rr = realp;
  #pragma unroll
  for (int off = 32; off; off >>= 1) {
    su += __shfl_down(su, off, 64);
    rr += __shfl_down(rr, off, 64);
  }
  if ((tid & 63) == 0) { scal_s[tid >> 6] = su; scal_m[tid >> 6] = rr; }
  __syncthreads();
  if (tid == 0) {
    float sumu    = (scal_s[0] + scal_s[1]) + (scal_s[2] + scal_s[3]);
    float realsum = (scal_m[0] + scal_m[1]) + (scal_m[2] + scal_m[3]);
    float total   = Q + C + __logf(sumu);
    atomicAdd(out, total - realsum);
  }
}

extern "C" void kernel_launch(void* const* d_in, const int* in_sizes, int n_in,
                              void* d_out, int out_size, void* d_ws, size_t ws_size,
                              hipStream_t stream) {
  const float* em  = (const float*)d_in[0];
  const int*   lab = (const int*)d_in[1];
  const float* tr  = (const float*)d_in[2];
  hipMemsetAsync(d_out, 0, sizeof(float), stream);
  crf_kernel<<<NB, 256, 0, stream>>>(em, lab, tr, (float*)d_out);
}